// Round 6
// baseline (470.470 us; speedup 1.0000x reference)
//
#include <hip/hip_runtime.h>

#define N_NODESC 50000
#define N_EDGESC 600000
#define HID 128
#define LAYERS 3
#define N_GRAPHSC 16
#define OUT_DIM 14
#define GEN_EPS 1e-7f
#define BN_EPS 1e-5f
#define SCAN_BLK 196     // ceil(50000/256)
#define POOL_BLK 400     // pool stage-1 blocks (125 rows each)
#define EMB_BLK 6250     // embed blocks (8 rows each)
#define GEMM_BLK 782     // ceil(50000/64)
#define XPAD 50048       // x rows padded to GEMM_BLK*64
#define LOG2E 1.44269504f

typedef short bf16x8 __attribute__((ext_vector_type(8)));
typedef float f32x4 __attribute__((ext_vector_type(4)));

__device__ __forceinline__ unsigned short f2bf(float f) {
    union { float f; unsigned u; } v; v.f = f;
    unsigned r = v.u + 0x7FFF + ((v.u >> 16) & 1);  // RNE
    return (unsigned short)(r >> 16);
}
__device__ __forceinline__ float bf_lo(unsigned u) {
    return __uint_as_float(u << 16);
}
__device__ __forceinline__ float bf_hi(unsigned u) {
    return __uint_as_float(u & 0xFFFF0000u);
}

// ---------------- CSR build ----------------
__global__ void k_count(const int* __restrict__ dst, int* __restrict__ deg) {
    int i = blockIdx.x * blockDim.x + threadIdx.x;
    if (i < N_EDGESC) atomicAdd(&deg[dst[i]], 1);
}

__global__ void k_blocksum(const int* __restrict__ deg, int* __restrict__ part) {
    __shared__ int sh[256];
    int t = threadIdx.x;
    int i = blockIdx.x * 256 + t;
    sh[t] = (i < N_NODESC) ? deg[i] : 0;
    __syncthreads();
    for (int off = 128; off > 0; off >>= 1) {
        if (t < off) sh[t] += sh[t + off];
        __syncthreads();
    }
    if (t == 0) part[blockIdx.x] = sh[0];
}

__global__ void k_scanpart(const int* __restrict__ part, int* __restrict__ bofs) {
    __shared__ int sh[256];
    int t = threadIdx.x;
    int v = (t < SCAN_BLK) ? part[t] : 0;
    sh[t] = v;
    __syncthreads();
    for (int off = 1; off < 256; off <<= 1) {
        int add = (t >= off) ? sh[t - off] : 0;
        __syncthreads();
        sh[t] += add;
        __syncthreads();
    }
    if (t < SCAN_BLK) bofs[t] = sh[t] - v;  // exclusive
}

__global__ void k_rowptr(const int* __restrict__ deg, const int* __restrict__ bofs,
                         int* __restrict__ row_ptr, int* __restrict__ cursor) {
    __shared__ int sh[256];
    int t = threadIdx.x;
    int i = blockIdx.x * 256 + t;
    int d = (i < N_NODESC) ? deg[i] : 0;
    sh[t] = d;
    __syncthreads();
    for (int off = 1; off < 256; off <<= 1) {
        int add = (t >= off) ? sh[t - off] : 0;
        __syncthreads();
        sh[t] += add;
        __syncthreads();
    }
    if (i < N_NODESC) {
        int rp = bofs[blockIdx.x] + sh[t] - d;
        row_ptr[i] = rp;
        cursor[i] = rp;
    }
    if (i == 0) row_ptr[N_NODESC] = N_EDGESC;
}

__global__ void k_scatter(const int* __restrict__ dst, const int* __restrict__ src,
                          const int* __restrict__ f0, const int* __restrict__ f1,
                          int* __restrict__ cursor, int* __restrict__ csr_pack) {
    int i = blockIdx.x * blockDim.x + threadIdx.x;
    if (i < N_EDGESC) {
        int pos = atomicAdd(&cursor[dst[i]], 1);
        csr_pack[pos] = src[i] | ((f0[i] * 3 + f1[i]) << 20);
    }
}

// W -> bf16 in MFMA B-fragment order
__global__ void k_wfrag(const float* __restrict__ W, unsigned short* __restrict__ wf) {
    int i = blockIdx.x * blockDim.x + threadIdx.x;
    if (i >= LAYERS * 4 * 8 * 64 * 8) return;
    int j = i & 7;
    int lane = (i >> 3) & 63;
    int nt = (i >> 9) & 7;
    int ks = (i >> 12) & 3;
    int l = i >> 14;
    int k = ks * 32 + (lane >> 4) * 8 + j;
    int n = nt * 16 + (lane & 15);
    wf[i] = f2bf(W[(size_t)l * HID * HID + k * HID + n]);
}

// ---------------- node embedding (+ BN partials for layer 0) ----------------
__global__ void k_embed(const int* __restrict__ f0, const int* __restrict__ f1,
                        const float4* __restrict__ W0, const float4* __restrict__ W1,
                        float4* __restrict__ hv4, float* __restrict__ part) {
    __shared__ float sh[1024], sh2[1024];
    int tid = threadIdx.x;
    int i = blockIdx.x * 256 + tid;
    int v = i >> 5, c4 = i & 31;
    float4 a = W0[f0[v] * 32 + c4];
    float4 b = W1[f1[v] * 32 + c4];
    float4 o = make_float4(a.x + b.x, a.y + b.y, a.z + b.z, a.w + b.w);
    hv4[i] = o;
    sh[tid * 4 + 0] = o.x; sh2[tid * 4 + 0] = o.x * o.x;
    sh[tid * 4 + 1] = o.y; sh2[tid * 4 + 1] = o.y * o.y;
    sh[tid * 4 + 2] = o.z; sh2[tid * 4 + 2] = o.z * o.z;
    sh[tid * 4 + 3] = o.w; sh2[tid * 4 + 3] = o.w * o.w;
    __syncthreads();
    if (tid < 128) {
        int c4i = tid >> 2, j = tid & 3;
        float s = 0.f, s2 = 0.f;
#pragma unroll
        for (int r = 0; r < 8; r++) {
            s += sh[(r * 32 + c4i) * 4 + j];
            s2 += sh2[(r * 32 + c4i) * 4 + j];
        }
        part[(size_t)blockIdx.x * 256 + tid] = s;
        part[(size_t)blockIdx.x * 256 + 128 + tid] = s2;
    }
}

// sum nparts partials -> gsum[256] (sum||sumsq); one block per slot
__global__ void k_bn_reduce2(const float* __restrict__ part, int nparts,
                             float* __restrict__ gsum) {
    int slot = blockIdx.x;
    int t = threadIdx.x;
    float s = 0.f;
    for (int p = t; p < nparts; p += 256) s += part[(size_t)p * 256 + slot];
    __shared__ float sh[256];
    sh[t] = s;
    __syncthreads();
    for (int o = 128; o > 0; o >>= 1) {
        if (t < o) sh[t] += sh[t + o];
        __syncthreads();
    }
    if (t == 0) gsum[slot] = sh[0];
}

// BN+ReLU -> bf16 pair-packed hv1; 4 channels/thread
__global__ void k_hv1b(const float4* __restrict__ hv4, const float* __restrict__ gsum,
                       const float* __restrict__ gamma, const float* __restrict__ betab,
                       uint2* __restrict__ hv1b) {
    int i = blockIdx.x * 256 + threadIdx.x;   // < 50000*32
    int c = (i & 31) * 4;
    const float invN = 1.f / (float)N_NODESC;
    float4 h = hv4[i];
    float r[4];
#pragma unroll
    for (int j = 0; j < 4; j++) {
        float mu = gsum[c + j] * invN;
        float var = gsum[128 + c + j] * invN - mu * mu;
        float sc = gamma[c + j] * rsqrtf(var + BN_EPS);
        float sf = betab[c + j] - mu * sc;
        r[j] = fmaxf(fmaf((&h.x)[j], sc, sf), 0.f);
    }
    uint2 o;
    o.x = (unsigned)f2bf(r[0]) | ((unsigned)f2bf(r[1]) << 16);
    o.y = (unsigned)f2bf(r[2]) | ((unsigned)f2bf(r[3]) << 16);
    hv1b[i] = o;
}

// ---------------- GENConv aggregation (scalarized edge descriptors) ---------
__global__ __launch_bounds__(256) void k_agg(
    const unsigned* __restrict__ hv1b, const int* __restrict__ row_ptr,
    const int* __restrict__ csr_pack, const float* __restrict__ e0,
    const float* __restrict__ e1, const float* __restrict__ beta_p,
    unsigned* __restrict__ xb) {
    __shared__ float2 sh_et[18 * 64];   // [f01][lane] -> channels (2*lane, 2*lane+1)
    int tid = threadIdx.x;
    for (int i = tid; i < 18 * 64; i += 256) {
        int f = i >> 6, ln = i & 63;
        int a = f / 3, b = f - 3 * a;
        float2 ea = *(const float2*)(e0 + a * HID + 2 * ln);
        float2 eb = *(const float2*)(e1 + b * HID + 2 * ln);
        sh_et[i] = make_float2(ea.x + eb.x, ea.y + eb.y);
    }
    int wave = tid >> 6, lane = tid & 63;
    int v = blockIdx.x * 4 + wave;
    float beta = *beta_p;
    const float bl2 = beta * LOG2E;           // exp(beta*m) = 2^(bl2*m)
    const float beps = bl2 * GEN_EPS;
    __syncthreads();
    if (v >= N_NODESC) return;
    unsigned su = hv1b[(size_t)v * 64 + lane];
    float h10 = bf_lo(su), h11 = bf_hi(su);
    int p0 = row_ptr[v], p1 = row_ptr[v + 1];
    int deg = p1 - p0;
    float n0 = 0.f, n1 = 0.f, d0 = 0.f, d1 = 0.f;

    // Per-edge: descriptor moved to SGPRs via readlane (wave-uniform j), so
    // unpack + gather base address run on the scalar pipe; eps folded out of
    // the loop (sum m*w = sum r*w + eps*sum w).
#define AGG_BODY(J)                                                         \
    {                                                                       \
        int pack = __builtin_amdgcn_readlane(pk, (J));                      \
        unsigned srcn = (unsigned)pack & 0xFFFFFu;                          \
        unsigned f01 = ((unsigned)pack) >> 20;                              \
        const unsigned* bp = hv1b + ((size_t)srcn << 6);                    \
        unsigned u = bp[lane];                                              \
        float2 t = sh_et[(f01 << 6) | lane];                                \
        float r0 = fmaxf(bf_lo(u) + t.x, 0.f);                              \
        float r1 = fmaxf(bf_hi(u) + t.y, 0.f);                              \
        float w0 = exp2f(fmaf(r0, bl2, beps));                              \
        float w1 = exp2f(fmaf(r1, bl2, beps));                              \
        d0 += w0; d1 += w1;                                                 \
        n0 = fmaf(r0, w0, n0); n1 = fmaf(r1, w1, n1);                       \
    }

    for (int base = 0; base < deg; base += 64) {
        int idx = base + lane;
        int pk = (idx < deg) ? csr_pack[p0 + idx] : 0;
        int jn = min(64, deg - base);
        int j = 0;
        for (; j + 2 <= jn; j += 2) {
            AGG_BODY(j)
            AGG_BODY(j + 1)
        }
        if (j < jn) AGG_BODY(j)
    }
#undef AGG_BODY

    float ox = h10 + (deg ? n0 / d0 + GEN_EPS : 0.f);
    float oy = h11 + (deg ? n1 / d1 + GEN_EPS : 0.f);
    xb[(size_t)v * 64 + lane] = (unsigned)f2bf(ox) | ((unsigned)f2bf(oy) << 16);
}

// ---------------- MFMA GEMM + bias + skip + next-layer BN partials ----------
__global__ __launch_bounds__(256) void k_gemm(
    const unsigned short* __restrict__ x,   // [XPAD][128] bf16
    const unsigned short* __restrict__ wf,  // [4][8][64][8] bf16 frags
    const float* __restrict__ b, float* __restrict__ hv,
    float* __restrict__ part) {
    __shared__ float shs[512], shs2[512];
    int tid = threadIdx.x;
    int w = tid >> 6, lane = tid & 63;
    int m0 = blockIdx.x * 64 + w * 16;
    int mrow = lane & 15, grp = lane >> 4;
    bf16x8 af[4];
    const unsigned short* xrow = x + (size_t)(m0 + mrow) * HID + grp * 8;
#pragma unroll
    for (int ks = 0; ks < 4; ks++)
        af[ks] = *(const bf16x8*)(xrow + ks * 32);
    f32x4 acc[8];
#pragma unroll
    for (int nt = 0; nt < 8; nt++) acc[nt] = (f32x4){0.f, 0.f, 0.f, 0.f};
#pragma unroll
    for (int nt = 0; nt < 8; nt++) {
#pragma unroll
        for (int ks = 0; ks < 4; ks++) {
            bf16x8 bf = *(const bf16x8*)(wf + (size_t)((ks * 8 + nt) * 64 + lane) * 8);
            acc[nt] = __builtin_amdgcn_mfma_f32_16x16x32_bf16(af[ks], bf, acc[nt], 0, 0, 0);
        }
    }
#pragma unroll
    for (int nt = 0; nt < 8; nt++) {
        int col = nt * 16 + mrow;
        float bias = b[col];
        float s = 0.f, s2 = 0.f;
#pragma unroll
        for (int r = 0; r < 4; r++) {
            int v = m0 + grp * 4 + r;
            if (v < N_NODESC) {
                size_t idx = (size_t)v * HID + col;
                float o = acc[nt][r] + bias + hv[idx];
                hv[idx] = o;
                s += o; s2 += o * o;
            }
        }
        s  += __shfl_xor(s, 16, 64);  s  += __shfl_xor(s, 32, 64);
        s2 += __shfl_xor(s2, 16, 64); s2 += __shfl_xor(s2, 32, 64);
        if (lane < 16) { shs[w * 128 + col] = s; shs2[w * 128 + col] = s2; }
    }
    __syncthreads();
    if (tid < 128) {
        part[(size_t)blockIdx.x * 256 + tid] =
            shs[tid] + shs[128 + tid] + shs[256 + tid] + shs[384 + tid];
    } else {
        int c = tid - 128;
        part[(size_t)blockIdx.x * 256 + tid] =
            shs2[c] + shs2[128 + c] + shs2[256 + c] + shs2[384 + c];
    }
}

// ---------------- pooling stage 1 ----------------
__global__ void k_pool(const float* __restrict__ hv, float* __restrict__ part2) {
    int tid = threadIdx.x;
    int c = tid & 127, rh = tid >> 7;
    int start = blockIdx.x * 125;
    float acc = 0.f;
    for (int r = start + rh; r < start + 125; r += 2)
        acc += hv[(size_t)r * HID + c];
    __shared__ float sh[256];
    sh[tid] = acc;
    __syncthreads();
    if (rh == 0) part2[blockIdx.x * 128 + c] = acc + sh[tid + 128];
}

// ---------------- pooling stage 2 + output linear (one block) ----------------
__global__ void k_finish(const float* __restrict__ part2, const float* __restrict__ Wo,
                         const float* __restrict__ bo, float* __restrict__ out) {
    __shared__ float hg[N_GRAPHSC * HID];
    int t = threadIdx.x;
    for (int s = t; s < N_GRAPHSC * HID; s += 256) {
        int g = s >> 7, c = s & 127;
        float x = 0.f;
#pragma unroll
        for (int i = 0; i < 25; i++) x += part2[(g * 25 + i) * 128 + c];
        hg[s] = x;
    }
    __syncthreads();
    if (t < N_GRAPHSC * OUT_DIM) {
        int g = t / OUT_DIM, o = t % OUT_DIM;
        const float inv = (float)N_GRAPHSC / (float)N_NODESC;
        float acc = bo[o];
        for (int k = 0; k < HID; k++)
            acc += hg[g * HID + k] * inv * Wo[k * OUT_DIM + o];
        out[t] = acc;
    }
}

extern "C" void kernel_launch(void* const* d_in, const int* in_sizes, int n_in,
                              void* d_out, int out_size, void* d_ws, size_t ws_size,
                              hipStream_t stream) {
    const int* node_feat0 = (const int*)d_in[0];
    const int* node_feat1 = (const int*)d_in[1];
    const int* edge_feat0 = (const int*)d_in[2];
    const int* edge_feat1 = (const int*)d_in[3];
    const int* edge_src   = (const int*)d_in[4];
    const int* edge_dst   = (const int*)d_in[5];
    const float* W_node0   = (const float*)d_in[8];
    const float* W_node1   = (const float*)d_in[9];
    const float* edge_emb0 = (const float*)d_in[10];
    const float* edge_emb1 = (const float*)d_in[11];
    const float* beta      = (const float*)d_in[12];
    const float* mlp_W     = (const float*)d_in[13];
    const float* mlp_b     = (const float*)d_in[14];
    const float* bn_gamma  = (const float*)d_in[15];
    const float* bn_beta   = (const float*)d_in[16];
    const float* W_out     = (const float*)d_in[17];
    const float* b_out     = (const float*)d_in[18];
    float* out = (float*)d_out;

    char* ws = (char*)d_ws;
    size_t off = 0;
    auto alloc = [&](size_t bytes) -> void* {
        void* p = ws + off;
        off += (bytes + 255) & ~(size_t)255;
        return p;
    };
    float* hv      = (float*)alloc((size_t)N_NODESC * HID * 4);
    unsigned* xb   = (unsigned*)alloc((size_t)XPAD * 64 * 4);      // bf16 pairs
    unsigned* hv1b = (unsigned*)alloc((size_t)N_NODESC * 64 * 4);  // bf16 pairs
    float* bnpart  = (float*)alloc((size_t)EMB_BLK * 256 * 4);
    float* gsum    = (float*)alloc(256 * 4);
    unsigned short* wfrag = (unsigned short*)alloc((size_t)LAYERS * 16384 * 2);
    float* part2   = (float*)alloc(POOL_BLK * 128 * 4);
    int* row_ptr   = (int*)alloc((N_NODESC + 1) * 4);
    int* cursor    = (int*)alloc(N_NODESC * 4);
    int* deg       = (int*)alloc(N_NODESC * 4);
    int* part      = (int*)alloc(SCAN_BLK * 4);
    int* bofs      = (int*)alloc(SCAN_BLK * 4);
    int* csr_pack  = (int*)alloc((size_t)N_EDGESC * 4);

    // ---- CSR build (edge_dst is layer-invariant) ----
    hipMemsetAsync(deg, 0, N_NODESC * 4, stream);
    k_count<<<(N_EDGESC + 255) / 256, 256, 0, stream>>>(edge_dst, deg);
    k_blocksum<<<SCAN_BLK, 256, 0, stream>>>(deg, part);
    k_scanpart<<<1, 256, 0, stream>>>(part, bofs);
    k_rowptr<<<SCAN_BLK, 256, 0, stream>>>(deg, bofs, row_ptr, cursor);
    k_scatter<<<(N_EDGESC + 255) / 256, 256, 0, stream>>>(
        edge_dst, edge_src, edge_feat0, edge_feat1, cursor, csr_pack);
    k_wfrag<<<(LAYERS * 16384 + 255) / 256, 256, 0, stream>>>(mlp_W, wfrag);

    // ---- node embedding (+ layer-0 BN partials) ----
    k_embed<<<EMB_BLK, 256, 0, stream>>>(
        node_feat0, node_feat1, (const float4*)W_node0, (const float4*)W_node1,
        (float4*)hv, bnpart);

    // ---- layers ----
    for (int l = 0; l < LAYERS; l++) {
        int nparts = (l == 0) ? EMB_BLK : GEMM_BLK;
        k_bn_reduce2<<<256, 256, 0, stream>>>(bnpart, nparts, gsum);
        k_hv1b<<<(N_NODESC * 32) / 256, 256, 0, stream>>>(
            (const float4*)hv, gsum, bn_gamma + l * HID, bn_beta + l * HID,
            (uint2*)hv1b);
        k_agg<<<(N_NODESC + 3) / 4, 256, 0, stream>>>(
            hv1b, row_ptr, csr_pack,
            edge_emb0 + (size_t)l * 6 * HID, edge_emb1 + (size_t)l * 3 * HID,
            beta + l, xb);
        k_gemm<<<GEMM_BLK, 256, 0, stream>>>(
            (const unsigned short*)xb, wfrag + (size_t)l * 16384,
            mlp_b + l * HID, hv, bnpart);
    }

    // ---- pooling + output ----
    k_pool<<<POOL_BLK, 256, 0, stream>>>(hv, part2);
    k_finish<<<1, 256, 0, stream>>>(part2, W_out, b_out, out);
}

// Round 7
// 454.905 us; speedup vs baseline: 1.0342x; 1.0342x over previous
//
#include <hip/hip_runtime.h>

#define N_NODESC 50000
#define N_EDGESC 600000
#define HID 128
#define LAYERS 3
#define N_GRAPHSC 16
#define OUT_DIM 14
#define GEN_EPS 1e-7f
#define BN_EPS 1e-5f
#define SCAN_BLK 196     // ceil(50000/256)
#define POOL_BLK 400     // pool stage-1 blocks (125 rows each)
#define EMB_BLK 6250     // embed blocks (8 rows each)
#define GEMM_BLK 782     // ceil(50000/64)
#define XPAD 50048       // x rows padded to GEMM_BLK*64
#define LOG2E 1.44269504f

typedef short bf16x8 __attribute__((ext_vector_type(8)));
typedef float f32x4 __attribute__((ext_vector_type(4)));

__device__ __forceinline__ unsigned short f2bf(float f) {
    union { float f; unsigned u; } v; v.f = f;
    unsigned r = v.u + 0x7FFF + ((v.u >> 16) & 1);  // RNE
    return (unsigned short)(r >> 16);
}
__device__ __forceinline__ float bf_lo(unsigned u) {
    return __uint_as_float(u << 16);
}
__device__ __forceinline__ float bf_hi(unsigned u) {
    return __uint_as_float(u & 0xFFFF0000u);
}

// ---------------- CSR build ----------------
__global__ void k_count(const int* __restrict__ dst, int* __restrict__ deg) {
    int i = blockIdx.x * blockDim.x + threadIdx.x;
    if (i < N_EDGESC) atomicAdd(&deg[dst[i]], 1);
}

__global__ void k_blocksum(const int* __restrict__ deg, int* __restrict__ part) {
    __shared__ int sh[256];
    int t = threadIdx.x;
    int i = blockIdx.x * 256 + t;
    sh[t] = (i < N_NODESC) ? deg[i] : 0;
    __syncthreads();
    for (int off = 128; off > 0; off >>= 1) {
        if (t < off) sh[t] += sh[t + off];
        __syncthreads();
    }
    if (t == 0) part[blockIdx.x] = sh[0];
}

__global__ void k_scanpart(const int* __restrict__ part, int* __restrict__ bofs) {
    __shared__ int sh[256];
    int t = threadIdx.x;
    int v = (t < SCAN_BLK) ? part[t] : 0;
    sh[t] = v;
    __syncthreads();
    for (int off = 1; off < 256; off <<= 1) {
        int add = (t >= off) ? sh[t - off] : 0;
        __syncthreads();
        sh[t] += add;
        __syncthreads();
    }
    if (t < SCAN_BLK) bofs[t] = sh[t] - v;  // exclusive
}

__global__ void k_rowptr(const int* __restrict__ deg, const int* __restrict__ bofs,
                         int* __restrict__ row_ptr, int* __restrict__ cursor) {
    __shared__ int sh[256];
    int t = threadIdx.x;
    int i = blockIdx.x * 256 + t;
    int d = (i < N_NODESC) ? deg[i] : 0;
    sh[t] = d;
    __syncthreads();
    for (int off = 1; off < 256; off <<= 1) {
        int add = (t >= off) ? sh[t - off] : 0;
        __syncthreads();
        sh[t] += add;
        __syncthreads();
    }
    if (i < N_NODESC) {
        int rp = bofs[blockIdx.x] + sh[t] - d;
        row_ptr[i] = rp;
        cursor[i] = rp;
    }
    if (i == 0) row_ptr[N_NODESC] = N_EDGESC;
}

// pack = (src<<8) | f01*8 : & 0xFFFFFF00 = byte row offset (x256 = x64 uints),
//                           & 0xFF       = byte offset into per-lane etab row
__global__ void k_scatter(const int* __restrict__ dst, const int* __restrict__ src,
                          const int* __restrict__ f0, const int* __restrict__ f1,
                          int* __restrict__ cursor, int* __restrict__ csr_pack) {
    int i = blockIdx.x * blockDim.x + threadIdx.x;
    if (i < N_EDGESC) {
        int pos = atomicAdd(&cursor[dst[i]], 1);
        csr_pack[pos] = (src[i] << 8) | ((f0[i] * 3 + f1[i]) * 8);
    }
}

// W -> bf16 in MFMA B-fragment order
__global__ void k_wfrag(const float* __restrict__ W, unsigned short* __restrict__ wf) {
    int i = blockIdx.x * blockDim.x + threadIdx.x;
    if (i >= LAYERS * 4 * 8 * 64 * 8) return;
    int j = i & 7;
    int lane = (i >> 3) & 63;
    int nt = (i >> 9) & 7;
    int ks = (i >> 12) & 3;
    int l = i >> 14;
    int k = ks * 32 + (lane >> 4) * 8 + j;
    int n = nt * 16 + (lane & 15);
    wf[i] = f2bf(W[(size_t)l * HID * HID + k * HID + n]);
}

// ---------------- node embedding (+ BN partials for layer 0) ----------------
__global__ void k_embed(const int* __restrict__ f0, const int* __restrict__ f1,
                        const float4* __restrict__ W0, const float4* __restrict__ W1,
                        float4* __restrict__ hv4, float* __restrict__ part) {
    __shared__ float sh[1024], sh2[1024];
    int tid = threadIdx.x;
    int i = blockIdx.x * 256 + tid;
    int v = i >> 5, c4 = i & 31;
    float4 a = W0[f0[v] * 32 + c4];
    float4 b = W1[f1[v] * 32 + c4];
    float4 o = make_float4(a.x + b.x, a.y + b.y, a.z + b.z, a.w + b.w);
    hv4[i] = o;
    sh[tid * 4 + 0] = o.x; sh2[tid * 4 + 0] = o.x * o.x;
    sh[tid * 4 + 1] = o.y; sh2[tid * 4 + 1] = o.y * o.y;
    sh[tid * 4 + 2] = o.z; sh2[tid * 4 + 2] = o.z * o.z;
    sh[tid * 4 + 3] = o.w; sh2[tid * 4 + 3] = o.w * o.w;
    __syncthreads();
    if (tid < 128) {
        int c4i = tid >> 2, j = tid & 3;
        float s = 0.f, s2 = 0.f;
#pragma unroll
        for (int r = 0; r < 8; r++) {
            s += sh[(r * 32 + c4i) * 4 + j];
            s2 += sh2[(r * 32 + c4i) * 4 + j];
        }
        part[(size_t)blockIdx.x * 256 + tid] = s;
        part[(size_t)blockIdx.x * 256 + 128 + tid] = s2;
    }
}

// sum nparts partials -> gsum[256] (sum||sumsq); one block per slot
__global__ void k_bn_reduce2(const float* __restrict__ part, int nparts,
                             float* __restrict__ gsum) {
    int slot = blockIdx.x;
    int t = threadIdx.x;
    float s = 0.f;
    for (int p = t; p < nparts; p += 256) s += part[(size_t)p * 256 + slot];
    __shared__ float sh[256];
    sh[t] = s;
    __syncthreads();
    for (int o = 128; o > 0; o >>= 1) {
        if (t < o) sh[t] += sh[t + o];
        __syncthreads();
    }
    if (t == 0) gsum[slot] = sh[0];
}

// BN+ReLU -> bf16 pair-packed hv1; 4 channels/thread
__global__ void k_hv1b(const float4* __restrict__ hv4, const float* __restrict__ gsum,
                       const float* __restrict__ gamma, const float* __restrict__ betab,
                       uint2* __restrict__ hv1b) {
    int i = blockIdx.x * 256 + threadIdx.x;   // < 50000*32
    int c = (i & 31) * 4;
    const float invN = 1.f / (float)N_NODESC;
    float4 h = hv4[i];
    float r[4];
#pragma unroll
    for (int j = 0; j < 4; j++) {
        float mu = gsum[c + j] * invN;
        float var = gsum[128 + c + j] * invN - mu * mu;
        float sc = gamma[c + j] * rsqrtf(var + BN_EPS);
        float sf = betab[c + j] - mu * sc;
        r[j] = fmaxf(fmaf((&h.x)[j], sc, sf), 0.f);
    }
    uint2 o;
    o.x = (unsigned)f2bf(r[0]) | ((unsigned)f2bf(r[1]) << 16);
    o.y = (unsigned)f2bf(r[2]) | ((unsigned)f2bf(r[3]) << 16);
    hv1b[i] = o;
}

// ---------------- GENConv aggregation (8 nodes/block, AND-only addressing) ---
__global__ __launch_bounds__(512) void k_agg(
    const unsigned* __restrict__ hv1b, const int* __restrict__ row_ptr,
    const int* __restrict__ csr_pack, const float* __restrict__ e0,
    const float* __restrict__ e1, const float* __restrict__ beta_p,
    unsigned* __restrict__ xb) {
    __shared__ float2 sh_et[64][19];  // [lane][f01]; stride 38 dwords (2-way = free)
    int tid = threadIdx.x;
    for (int i = tid; i < 18 * 64; i += 512) {
        int f = i >> 6, ln = i & 63;
        int a = f / 3, b = f - 3 * a;
        float2 ea = *(const float2*)(e0 + a * HID + 2 * ln);
        float2 eb = *(const float2*)(e1 + b * HID + 2 * ln);
        sh_et[ln][f] = make_float2(ea.x + eb.x, ea.y + eb.y);
    }
    int wave = tid >> 6, lane = tid & 63;
    int v = blockIdx.x * 8 + wave;           // grid*8 == 50000 exactly
    float beta = *beta_p;
    const float bl2 = beta * LOG2E;          // exp(beta*m)=2^(bl2*m); const scale cancels
    __syncthreads();
    unsigned su = hv1b[(size_t)v * 64 + lane];
    float h10 = bf_lo(su), h11 = bf_hi(su);
    int p0 = row_ptr[v], p1 = row_ptr[v + 1];
    int deg = p1 - p0;
    float n0 = 0.f, n1 = 0.f, d0 = 0.f, d1 = 0.f;
    const char* hv1c = (const char*)hv1b;
    const char* etc = (const char*)&sh_et[lane][0];
    unsigned lane4 = (unsigned)lane * 4;

#define AGG_BODY(J)                                                         \
    {                                                                       \
        int pack = __shfl(pk, (J), 64);                                     \
        unsigned u = *(const unsigned*)(hv1c +                              \
                        ((((unsigned)pack) & 0xFFFFFF00u) + lane4));        \
        float2 t = *(const float2*)(etc + (((unsigned)pack) & 0xFFu));      \
        float r0 = fmaxf(bf_lo(u) + t.x, 0.f);                              \
        float r1 = fmaxf(bf_hi(u) + t.y, 0.f);                              \
        float w0 = exp2f(r0 * bl2);                                         \
        float w1 = exp2f(r1 * bl2);                                         \
        d0 += w0; d1 += w1;                                                 \
        n0 = fmaf(r0, w0, n0); n1 = fmaf(r1, w1, n1);                       \
    }

    for (int base = 0; base < deg; base += 64) {
        int idx = base + lane;
        int pk = (idx < deg) ? csr_pack[p0 + idx] : 0;
        int jn = min(64, deg - base);
        int j = 0;
        for (; j + 2 <= jn; j += 2) {
            AGG_BODY(j)
            AGG_BODY(j + 1)
        }
        if (j < jn) AGG_BODY(j)
    }
#undef AGG_BODY

    float ox = h10 + (deg ? __fdividef(n0, d0) + GEN_EPS : 0.f);
    float oy = h11 + (deg ? __fdividef(n1, d1) + GEN_EPS : 0.f);
    xb[(size_t)v * 64 + lane] = (unsigned)f2bf(ox) | ((unsigned)f2bf(oy) << 16);
}

// ---------------- MFMA GEMM + bias + skip + next-layer BN partials ----------
__global__ __launch_bounds__(256) void k_gemm(
    const unsigned short* __restrict__ x,   // [XPAD][128] bf16
    const unsigned short* __restrict__ wf,  // [4][8][64][8] bf16 frags
    const float* __restrict__ b, float* __restrict__ hv,
    float* __restrict__ part) {
    __shared__ float shs[512], shs2[512];
    int tid = threadIdx.x;
    int w = tid >> 6, lane = tid & 63;
    int m0 = blockIdx.x * 64 + w * 16;
    int mrow = lane & 15, grp = lane >> 4;
    bf16x8 af[4];
    const unsigned short* xrow = x + (size_t)(m0 + mrow) * HID + grp * 8;
#pragma unroll
    for (int ks = 0; ks < 4; ks++)
        af[ks] = *(const bf16x8*)(xrow + ks * 32);
    f32x4 acc[8];
#pragma unroll
    for (int nt = 0; nt < 8; nt++) acc[nt] = (f32x4){0.f, 0.f, 0.f, 0.f};
#pragma unroll
    for (int nt = 0; nt < 8; nt++) {
#pragma unroll
        for (int ks = 0; ks < 4; ks++) {
            bf16x8 bf = *(const bf16x8*)(wf + (size_t)((ks * 8 + nt) * 64 + lane) * 8);
            acc[nt] = __builtin_amdgcn_mfma_f32_16x16x32_bf16(af[ks], bf, acc[nt], 0, 0, 0);
        }
    }
#pragma unroll
    for (int nt = 0; nt < 8; nt++) {
        int col = nt * 16 + mrow;
        float bias = b[col];
        float s = 0.f, s2 = 0.f;
#pragma unroll
        for (int r = 0; r < 4; r++) {
            int v = m0 + grp * 4 + r;
            if (v < N_NODESC) {
                size_t idx = (size_t)v * HID + col;
                float o = acc[nt][r] + bias + hv[idx];
                hv[idx] = o;
                s += o; s2 += o * o;
            }
        }
        s  += __shfl_xor(s, 16, 64);  s  += __shfl_xor(s, 32, 64);
        s2 += __shfl_xor(s2, 16, 64); s2 += __shfl_xor(s2, 32, 64);
        if (lane < 16) { shs[w * 128 + col] = s; shs2[w * 128 + col] = s2; }
    }
    __syncthreads();
    if (tid < 128) {
        part[(size_t)blockIdx.x * 256 + tid] =
            shs[tid] + shs[128 + tid] + shs[256 + tid] + shs[384 + tid];
    } else {
        int c = tid - 128;
        part[(size_t)blockIdx.x * 256 + tid] =
            shs2[c] + shs2[128 + c] + shs2[256 + c] + shs2[384 + c];
    }
}

// ---------------- pooling stage 1 ----------------
__global__ void k_pool(const float* __restrict__ hv, float* __restrict__ part2) {
    int tid = threadIdx.x;
    int c = tid & 127, rh = tid >> 7;
    int start = blockIdx.x * 125;
    float acc = 0.f;
    for (int r = start + rh; r < start + 125; r += 2)
        acc += hv[(size_t)r * HID + c];
    __shared__ float sh[256];
    sh[tid] = acc;
    __syncthreads();
    if (rh == 0) part2[blockIdx.x * 128 + c] = acc + sh[tid + 128];
}

// ---------------- pooling stage 2 + output linear (one block) ----------------
__global__ void k_finish(const float* __restrict__ part2, const float* __restrict__ Wo,
                         const float* __restrict__ bo, float* __restrict__ out) {
    __shared__ float hg[N_GRAPHSC * HID];
    int t = threadIdx.x;
    for (int s = t; s < N_GRAPHSC * HID; s += 256) {
        int g = s >> 7, c = s & 127;
        float x = 0.f;
#pragma unroll
        for (int i = 0; i < 25; i++) x += part2[(g * 25 + i) * 128 + c];
        hg[s] = x;
    }
    __syncthreads();
    if (t < N_GRAPHSC * OUT_DIM) {
        int g = t / OUT_DIM, o = t % OUT_DIM;
        const float inv = (float)N_GRAPHSC / (float)N_NODESC;
        float acc = bo[o];
        for (int k = 0; k < HID; k++)
            acc += hg[g * HID + k] * inv * Wo[k * OUT_DIM + o];
        out[t] = acc;
    }
}

extern "C" void kernel_launch(void* const* d_in, const int* in_sizes, int n_in,
                              void* d_out, int out_size, void* d_ws, size_t ws_size,
                              hipStream_t stream) {
    const int* node_feat0 = (const int*)d_in[0];
    const int* node_feat1 = (const int*)d_in[1];
    const int* edge_feat0 = (const int*)d_in[2];
    const int* edge_feat1 = (const int*)d_in[3];
    const int* edge_src   = (const int*)d_in[4];
    const int* edge_dst   = (const int*)d_in[5];
    const float* W_node0   = (const float*)d_in[8];
    const float* W_node1   = (const float*)d_in[9];
    const float* edge_emb0 = (const float*)d_in[10];
    const float* edge_emb1 = (const float*)d_in[11];
    const float* beta      = (const float*)d_in[12];
    const float* mlp_W     = (const float*)d_in[13];
    const float* mlp_b     = (const float*)d_in[14];
    const float* bn_gamma  = (const float*)d_in[15];
    const float* bn_beta   = (const float*)d_in[16];
    const float* W_out     = (const float*)d_in[17];
    const float* b_out     = (const float*)d_in[18];
    float* out = (float*)d_out;

    char* ws = (char*)d_ws;
    size_t off = 0;
    auto alloc = [&](size_t bytes) -> void* {
        void* p = ws + off;
        off += (bytes + 255) & ~(size_t)255;
        return p;
    };
    float* hv      = (float*)alloc((size_t)N_NODESC * HID * 4);
    unsigned* xb   = (unsigned*)alloc((size_t)XPAD * 64 * 4);      // bf16 pairs
    unsigned* hv1b = (unsigned*)alloc((size_t)N_NODESC * 64 * 4);  // bf16 pairs
    float* bnpart  = (float*)alloc((size_t)EMB_BLK * 256 * 4);
    float* gsum    = (float*)alloc(256 * 4);
    unsigned short* wfrag = (unsigned short*)alloc((size_t)LAYERS * 16384 * 2);
    float* part2   = (float*)alloc(POOL_BLK * 128 * 4);
    int* row_ptr   = (int*)alloc((N_NODESC + 1) * 4);
    int* cursor    = (int*)alloc(N_NODESC * 4);
    int* deg       = (int*)alloc(N_NODESC * 4);
    int* part      = (int*)alloc(SCAN_BLK * 4);
    int* bofs      = (int*)alloc(SCAN_BLK * 4);
    int* csr_pack  = (int*)alloc((size_t)N_EDGESC * 4);

    // ---- CSR build (edge_dst is layer-invariant) ----
    hipMemsetAsync(deg, 0, N_NODESC * 4, stream);
    k_count<<<(N_EDGESC + 255) / 256, 256, 0, stream>>>(edge_dst, deg);
    k_blocksum<<<SCAN_BLK, 256, 0, stream>>>(deg, part);
    k_scanpart<<<1, 256, 0, stream>>>(part, bofs);
    k_rowptr<<<SCAN_BLK, 256, 0, stream>>>(deg, bofs, row_ptr, cursor);
    k_scatter<<<(N_EDGESC + 255) / 256, 256, 0, stream>>>(
        edge_dst, edge_src, edge_feat0, edge_feat1, cursor, csr_pack);
    k_wfrag<<<(LAYERS * 16384 + 255) / 256, 256, 0, stream>>>(mlp_W, wfrag);

    // ---- node embedding (+ layer-0 BN partials) ----
    k_embed<<<EMB_BLK, 256, 0, stream>>>(
        node_feat0, node_feat1, (const float4*)W_node0, (const float4*)W_node1,
        (float4*)hv, bnpart);

    // ---- layers ----
    for (int l = 0; l < LAYERS; l++) {
        int nparts = (l == 0) ? EMB_BLK : GEMM_BLK;
        k_bn_reduce2<<<256, 256, 0, stream>>>(bnpart, nparts, gsum);
        k_hv1b<<<(N_NODESC * 32) / 256, 256, 0, stream>>>(
            (const float4*)hv, gsum, bn_gamma + l * HID, bn_beta + l * HID,
            (uint2*)hv1b);
        k_agg<<<N_NODESC / 8, 512, 0, stream>>>(
            hv1b, row_ptr, csr_pack,
            edge_emb0 + (size_t)l * 6 * HID, edge_emb1 + (size_t)l * 3 * HID,
            beta + l, xb);
        k_gemm<<<GEMM_BLK, 256, 0, stream>>>(
            (const unsigned short*)xb, wfrag + (size_t)l * 16384,
            mlp_b + l * HID, hv, bnpart);
    }

    // ---- pooling + output ----
    k_pool<<<POOL_BLK, 256, 0, stream>>>(hv, part2);
    k_finish<<<1, 256, 0, stream>>>(part2, W_out, b_out, out);
}